// Round 5
// baseline (309.527 us; speedup 1.0000x reference)
//
#include <hip/hip_runtime.h>
#include <hip/hip_cooperative_groups.h>

namespace cg = cooperative_groups;

#define TSEQ 1024
#define HIDV 64
#define NHEADS 16      // N*H = 2*8
#define LCH 64         // chunk length
#define NCH 16         // TSEQ/LCH
#define EMBED 512
#define CTX_FLOATS (NHEADS * TSEQ * HIDV)           // 1048576
#define EPSV 1e-6f
#define PIH 1.5707963267948966f

typedef short bf16x8 __attribute__((ext_vector_type(8)));
typedef float f32x4 __attribute__((ext_vector_type(4)));

__device__ __forceinline__ float relu_f(float x) { return fmaxf(x, 0.0f); }
__device__ __forceinline__ ushort f2bf(float f) {
    uint u = __float_as_uint(f);
    u += 0x7FFF + ((u >> 16) & 1);          // RNE
    return (ushort)(u >> 16);
}
__device__ __forceinline__ float bf2f(ushort h) { return __uint_as_float(((uint)h) << 16); }
__device__ __forceinline__ uint pk2(float a, float b) {
    return (uint)f2bf(a) | ((uint)f2bf(b) << 16);
}

// LDS layout (phase-overlaid), 58368 B total -> 2 blocks/CU
#define SMEM_BYTES 58368
// P3 offsets
#define OFF_QW 0          // ushort[64*136]  17408
#define OFF_KW 17408      // ushort[64*136]  17408
#define OFF_PT 34816      // ushort[32*136]   8704
#define OFF_VT 43520      // ushort[32*72]    4608
#define OFF_AM 48128      // ushort[64*72]    9216
#define OFF_PSUM 57344    // float[128]        512
#define OFF_DENA 57856    // float[64]         256
#define OFF_DENI 58112    // float[64]         256
// P1 offsets: kwT ushort[128*88] @0 (22528), vT1 ushort[64*88] @22528 (11264)
// P4 offsets: Ab ushort[32*72] @0 (4608), Bb ushort[64*72] @4608 (9216)

__global__ __launch_bounds__(256) void k_fused(
    const float* __restrict__ Q, const float* __restrict__ K,
    const float* __restrict__ V, const float* __restrict__ W,
    const float* __restrict__ bias, float* __restrict__ out,
    ushort* __restrict__ S16, float* __restrict__ ksumws,
    ushort* __restrict__ Ptg, float* __restrict__ attn2,
    float4* __restrict__ probs4)
{
    __shared__ __align__(16) char smem[SMEM_BYTES];
    cg::grid_group grid = cg::this_grid();

    const int bid = blockIdx.x;        // 0..511
    const int tid = threadIdx.x;       // 0..255
    const int w = tid >> 6, lane = tid & 63;
    const int quad = lane >> 4, l15 = lane & 15;

    // ============ Phase 1: chunk sums (blocks 0..255) | probs-zero (256..511)
    if (bid < 256) {
        ushort* kwT = (ushort*)smem;             // [dd=128][i=64] stride 88
        ushort* vT1 = (ushort*)(smem + 22528);   // [m=64][i=64] stride 88
        const int pair = bid;
        const int b = pair >> 4, c = pair & 15;
        const int l0 = c * LCH;

        #pragma unroll
        for (int s = 0; s < 4; ++s) {
            int e = tid + s * 256;               // f4 over 64x64
            int i = e >> 4, d = (e & 15) * 4;
            float4 k4 = *(const float4*)(K + (size_t)(b * TSEQ + l0 + i) * HIDV + d);
            float si, ci;
            __sincosf(PIH * (float)(l0 + i + 1) * (1.0f / 1024.0f), &si, &ci);
            float kv[4] = {relu_f(k4.x), relu_f(k4.y), relu_f(k4.z), relu_f(k4.w)};
            #pragma unroll
            for (int j = 0; j < 4; ++j) {
                kwT[(d + j) * 88 + i] = f2bf(si * kv[j]);
                kwT[(d + 64 + j) * 88 + i] = f2bf(ci * kv[j]);
            }
            float4 v4 = *(const float4*)(V + ((size_t)(l0 + i) * NHEADS + b) * HIDV + d);
            float vv[4] = {v4.x, v4.y, v4.z, v4.w};
            #pragma unroll
            for (int j = 0; j < 4; ++j) vT1[(d + j) * 88 + i] = f2bf(vv[j]);
        }
        __syncthreads();

        f32x4 acc[2][4];
        #pragma unroll
        for (int ii = 0; ii < 2; ++ii)
            #pragma unroll
            for (int mt = 0; mt < 4; ++mt) acc[ii][mt] = (f32x4){0.f, 0.f, 0.f, 0.f};
        #pragma unroll
        for (int ii = 0; ii < 2; ++ii) {
            int itv = w + ii * 4;                // dd-tile 0..7
            bf16x8 af[2];
            #pragma unroll
            for (int kk = 0; kk < 2; ++kk)
                af[kk] = *(const bf16x8*)(kwT + (itv * 16 + l15) * 88 + kk * 32 + quad * 8);
            #pragma unroll
            for (int mt = 0; mt < 4; ++mt)
                #pragma unroll
                for (int kk = 0; kk < 2; ++kk) {
                    bf16x8 bf = *(const bf16x8*)(vT1 + (mt * 16 + l15) * 88 + kk * 32 + quad * 8);
                    acc[ii][mt] = __builtin_amdgcn_mfma_f32_16x16x32_bf16(af[kk], bf, acc[ii][mt], 0, 0, 0);
                }
        }
        // store S^T bf16 [m][dd]
        ushort* SpT = S16 + (size_t)pair * 8192;
        #pragma unroll
        for (int ii = 0; ii < 2; ++ii)
            #pragma unroll
            for (int mt = 0; mt < 4; ++mt) {
                int m = mt * 16 + l15;
                int ddb = (w + ii * 4) * 16 + quad * 4;
                uint2 pk = make_uint2(pk2(acc[ii][mt][0], acc[ii][mt][1]),
                                      pk2(acc[ii][mt][2], acc[ii][mt][3]));
                *(uint2*)(SpT + m * 128 + ddb) = pk;
            }
        if (tid < 128) {
            float ssum = 0.f;
            #pragma unroll
            for (int ss = 0; ss < 8; ++ss) {
                uint4 u = *(const uint4*)(kwT + tid * 88 + ss * 8);
                ssum += bf2f((ushort)(u.x & 0xffff)) + bf2f((ushort)(u.x >> 16));
                ssum += bf2f((ushort)(u.y & 0xffff)) + bf2f((ushort)(u.y >> 16));
                ssum += bf2f((ushort)(u.z & 0xffff)) + bf2f((ushort)(u.z >> 16));
                ssum += bf2f((ushort)(u.w & 0xffff)) + bf2f((ushort)(u.w >> 16));
            }
            ksumws[(size_t)pair * 128 + tid] = ssum;
        }
    } else {
        // zero first 32 MB of probs
        float4 z = make_float4(0.f, 0.f, 0.f, 0.f);
        size_t base = (size_t)(bid - 256) * 8192 + tid;
        #pragma unroll
        for (int s = 0; s < 32; ++s) probs4[base + s * 256] = z;
    }

    grid.sync();

    // ============ Phase 2: exclusive prefix scan -> Ptg (bf16), psum (fp32)
    {
        int g = bid * 256 + tid;                 // 0..131071
        int bs = g >> 13, idx = g & 8191;
        const ushort* Sp = S16 + (size_t)bs * 131072 + idx;
        ushort* Pp = Ptg + (size_t)bs * 131072 + idx;
        float acc = 0.f;
        #pragma unroll
        for (int c = 0; c < NCH; ++c) {
            float t = bf2f(Sp[c * 8192]);
            Pp[c * 8192] = f2bf(acc);
            acc += t;
        }
        if (g < NHEADS * 128) {
            int b2 = g >> 7, i2 = g & 127;
            float a2 = 0.f;
            #pragma unroll
            for (int c = 0; c < NCH; ++c) {
                float* p = ksumws + (size_t)(b2 * NCH + c) * 128 + i2;
                float t = *p; *p = a2; a2 += t;
            }
        }
    }

    grid.sync();

    // ============ Phase 3: attention. 2 blocks per (b,c): m-halves.
    {
        ushort* qw = (ushort*)(smem + OFF_QW);    // [i][dd] stride 136
        ushort* kw = (ushort*)(smem + OFF_KW);    // [j][dd] stride 136
        ushort* Pt = (ushort*)(smem + OFF_PT);    // [m(32)][dd] stride 136
        ushort* vT = (ushort*)(smem + OFF_VT);    // [m(32)][j] stride 72
        ushort* Am = (ushort*)(smem + OFF_AM);    // [i][j] stride 72
        float* psum = (float*)(smem + OFF_PSUM);
        float* denA = (float*)(smem + OFF_DENA);
        float* denI = (float*)(smem + OFF_DENI);

        const int pair = bid >> 1, mh = bid & 1, m0b = mh * 32;
        const int b = pair >> 4, c = pair & 15;
        const int l0 = c * LCH;

        #pragma unroll
        for (int s = 0; s < 4; ++s) {
            int e = tid + s * 256;
            int i = e >> 4, d = (e & 15) * 4;
            float si, ci;
            __sincosf(PIH * (float)(l0 + i + 1) * (1.0f / 1024.0f), &si, &ci);
            float4 q4 = *(const float4*)(Q + (size_t)(b * TSEQ + l0 + i) * HIDV + d);
            float qv[4] = {relu_f(q4.x), relu_f(q4.y), relu_f(q4.z), relu_f(q4.w)};
            *(uint2*)(qw + i * 136 + d) = make_uint2(pk2(si * qv[0], si * qv[1]), pk2(si * qv[2], si * qv[3]));
            *(uint2*)(qw + i * 136 + 64 + d) = make_uint2(pk2(ci * qv[0], ci * qv[1]), pk2(ci * qv[2], ci * qv[3]));
            float4 k4 = *(const float4*)(K + (size_t)(b * TSEQ + l0 + i) * HIDV + d);
            float kv[4] = {relu_f(k4.x), relu_f(k4.y), relu_f(k4.z), relu_f(k4.w)};
            *(uint2*)(kw + i * 136 + d) = make_uint2(pk2(si * kv[0], si * kv[1]), pk2(si * kv[2], si * kv[3]));
            *(uint2*)(kw + i * 136 + 64 + d) = make_uint2(pk2(ci * kv[0], ci * kv[1]), pk2(ci * kv[2], ci * kv[3]));
        }
        {   // Pt: straight uint4 copies (already bf16 + [m][dd]); 32 rows x 128 dd
            const ushort* Pg = Ptg + (size_t)pair * 8192;
            #pragma unroll
            for (int s = 0; s < 2; ++s) {
                int e = tid + s * 256;               // 0..511 uint4 chunks
                int mrow = e >> 4, dd8 = (e & 15) * 8;
                *(uint4*)(Pt + mrow * 136 + dd8) = *(const uint4*)(Pg + (m0b + mrow) * 128 + dd8);
            }
        }
        #pragma unroll
        for (int s = 0; s < 2; ++s) {
            int e = tid + s * 256;
            int j = e >> 3, mf = (e & 7) * 4;
            float4 v4 = *(const float4*)(V + ((size_t)(l0 + j) * NHEADS + b) * HIDV + m0b + mf);
            vT[(mf + 0) * 72 + j] = f2bf(v4.x);
            vT[(mf + 1) * 72 + j] = f2bf(v4.y);
            vT[(mf + 2) * 72 + j] = f2bf(v4.z);
            vT[(mf + 3) * 72 + j] = f2bf(v4.w);
        }
        if (tid < 128) psum[tid] = ksumws[(size_t)pair * 128 + tid];
        __syncthreads();

        const int it = w;
        bf16x8 af[4];
        #pragma unroll
        for (int kk = 0; kk < 4; ++kk)
            af[kk] = *(const bf16x8*)(qw + (it * 16 + l15) * 136 + kk * 32 + quad * 8);

        // QK^T
        f32x4 accA[4];
        #pragma unroll
        for (int jt = 0; jt < 4; ++jt) {
            accA[jt] = (f32x4){0.f, 0.f, 0.f, 0.f};
            #pragma unroll
            for (int kk = 0; kk < 4; ++kk) {
                bf16x8 bf = *(const bf16x8*)(kw + (jt * 16 + l15) * 136 + kk * 32 + quad * 8);
                accA[jt] = __builtin_amdgcn_mfma_f32_16x16x32_bf16(af[kk], bf, accA[jt], 0, 0, 0);
            }
        }
        // mask + Am + row sums (each wave owns its 16 rows)
        {
            float rsum[4] = {0.f, 0.f, 0.f, 0.f};
            #pragma unroll
            for (int jt = 0; jt < 4; ++jt) {
                int j = jt * 16 + l15;
                #pragma unroll
                for (int r = 0; r < 4; ++r) {
                    int i = it * 16 + quad * 4 + r;
                    float val = (j <= i) ? accA[jt][r] : 0.f;
                    Am[i * 72 + j] = f2bf(val);
                    rsum[r] += val;
                }
            }
            #pragma unroll
            for (int off = 1; off < 16; off <<= 1) {
                rsum[0] += __shfl_xor(rsum[0], off);
                rsum[1] += __shfl_xor(rsum[1], off);
                rsum[2] += __shfl_xor(rsum[2], off);
                rsum[3] += __shfl_xor(rsum[3], off);
            }
            if (l15 == 0) {
                #pragma unroll
                for (int r = 0; r < 4; ++r) denA[it * 16 + quad * 4 + r] = rsum[r];
            }
        }
        // inter-chunk denominator (wave 0)
        if (tid < 64) {
            float s = 0.f;
            #pragma unroll
            for (int ss = 0; ss < 16; ++ss) {
                uint4 u = *(const uint4*)(qw + tid * 136 + ss * 8);
                s += bf2f((ushort)(u.x & 0xffff)) * psum[ss * 8 + 0] + bf2f((ushort)(u.x >> 16)) * psum[ss * 8 + 1];
                s += bf2f((ushort)(u.y & 0xffff)) * psum[ss * 8 + 2] + bf2f((ushort)(u.y >> 16)) * psum[ss * 8 + 3];
                s += bf2f((ushort)(u.z & 0xffff)) * psum[ss * 8 + 4] + bf2f((ushort)(u.z >> 16)) * psum[ss * 8 + 5];
                s += bf2f((ushort)(u.w & 0xffff)) * psum[ss * 8 + 6] + bf2f((ushort)(u.w >> 16)) * psum[ss * 8 + 7];
            }
            denI[tid] = s;
        }
        __syncthreads();

        // O = qw*P + Am*V  (2 m-tiles of 16 within this block's 32-col half)
        f32x4 accO[2];
        #pragma unroll
        for (int mm = 0; mm < 2; ++mm) {
            accO[mm] = (f32x4){0.f, 0.f, 0.f, 0.f};
            #pragma unroll
            for (int kk = 0; kk < 4; ++kk) {
                bf16x8 bp = *(const bf16x8*)(Pt + (mm * 16 + l15) * 136 + kk * 32 + quad * 8);
                accO[mm] = __builtin_amdgcn_mfma_f32_16x16x32_bf16(af[kk], bp, accO[mm], 0, 0, 0);
            }
        }
        bf16x8 aA[2];
        #pragma unroll
        for (int kk = 0; kk < 2; ++kk)
            aA[kk] = *(const bf16x8*)(Am + (it * 16 + l15) * 72 + kk * 32 + quad * 8);
        #pragma unroll
        for (int mm = 0; mm < 2; ++mm)
            #pragma unroll
            for (int kk = 0; kk < 2; ++kk) {
                bf16x8 bv = *(const bf16x8*)(vT + (mm * 16 + l15) * 72 + kk * 32 + quad * 8);
                accO[mm] = __builtin_amdgcn_mfma_f32_16x16x32_bf16(aA[kk], bv, accO[mm], 0, 0, 0);
            }

        const int nb = b >> 3, hh = b & 7;
        #pragma unroll
        for (int r = 0; r < 4; ++r) {
            int i = it * 16 + quad * 4 + r;
            float inv = 1.0f / fmaxf(denA[i] + denI[i], EPSV);
            #pragma unroll
            for (int mm = 0; mm < 2; ++mm) {
                int m = m0b + mm * 16 + l15;
                attn2[(size_t)((l0 + i) * 2 + nb) * EMBED + hh * 64 + m] = accO[mm][r] * inv;
            }
        }
    }

    grid.sync();

    // ============ Phase 4: out projection, 32x64 tiles (exactly 512 tasks)
    {
        ushort* Ab = (ushort*)smem;              // [32][72]
        ushort* Bb = (ushort*)(smem + 4608);     // [64][72]
        const int rt = bid >> 3, et = bid & 7;
        const int r0 = rt * 32, e0 = et * 64;
        const int it4 = w >> 1, jt0 = (w & 1) * 2;
        f32x4 acc4[2];
        acc4[0] = (f32x4){0.f, 0.f, 0.f, 0.f};
        acc4[1] = (f32x4){0.f, 0.f, 0.f, 0.f};

        for (int f0 = 0; f0 < EMBED; f0 += 64) {
            __syncthreads();
            #pragma unroll
            for (int s = 0; s < 2; ++s) {
                int e = tid + s * 256;
                int rr = e >> 4, ff = (e & 15) * 4;
                float4 a4 = *(const float4*)(attn2 + (size_t)(r0 + rr) * EMBED + f0 + ff);
                *(uint2*)(Ab + rr * 72 + ff) = make_uint2(pk2(a4.x, a4.y), pk2(a4.z, a4.w));
            }
            #pragma unroll
            for (int s = 0; s < 4; ++s) {
                int e = tid + s * 256;
                int rr = e >> 4, ff = (e & 15) * 4;
                float4 w4 = *(const float4*)(W + (size_t)(e0 + rr) * EMBED + f0 + ff);
                *(uint2*)(Bb + rr * 72 + ff) = make_uint2(pk2(w4.x, w4.y), pk2(w4.z, w4.w));
            }
            __syncthreads();
            bf16x8 af2[2];
            #pragma unroll
            for (int kk = 0; kk < 2; ++kk)
                af2[kk] = *(const bf16x8*)(Ab + (it4 * 16 + l15) * 72 + kk * 32 + quad * 8);
            #pragma unroll
            for (int jj = 0; jj < 2; ++jj) {
                int jt = jt0 + jj;
                #pragma unroll
                for (int kk = 0; kk < 2; ++kk) {
                    bf16x8 bf = *(const bf16x8*)(Bb + (jt * 16 + l15) * 72 + kk * 32 + quad * 8);
                    acc4[jj] = __builtin_amdgcn_mfma_f32_16x16x32_bf16(af2[kk], bf, acc4[jj], 0, 0, 0);
                }
            }
        }
        #pragma unroll
        for (int jj = 0; jj < 2; ++jj) {
            int e = e0 + (jt0 + jj) * 16 + l15;
            float be = bias[e];
            int h = e >> 6, m = e & 63;
            #pragma unroll
            for (int r = 0; r < 4; ++r) {
                int rr = r0 + it4 * 16 + quad * 4 + r;
                int t = rr >> 1, n = rr & 1;
                out[((size_t)(n * 8 + h) * TSEQ + t) * HIDV + m] = acc4[jj][r] + be;
            }
        }
    }

    // ============ tail: zero remaining 32 MB of probs
    {
        float4 z = make_float4(0.f, 0.f, 0.f, 0.f);
        size_t base = 2097152 + (size_t)bid * 4096 + tid;
        #pragma unroll
        for (int s = 0; s < 16; ++s) probs4[base + s * 256] = z;
    }
}

// ---------------------------------------------------------------------------
extern "C" void kernel_launch(void* const* d_in, const int* in_sizes, int n_in,
                              void* d_out, int out_size, void* d_ws, size_t ws_size,
                              hipStream_t stream) {
    const float* q = (const float*)d_in[0];
    const float* k = (const float*)d_in[1];
    const float* v = (const float*)d_in[2];
    const float* W = (const float*)d_in[3];
    const float* bias = (const float*)d_in[4];
    float* out = (float*)d_out;
    float* ws = (float*)d_ws;

    ushort* S16 = (ushort*)ws;                       // 2,097,152 ushorts
    float* ksum_ws = ws + 1048576;                   // 32,768 floats
    ushort* Ptg = (ushort*)(ws + 1048576 + 32768);   // 2,097,152 ushorts
    float* attn2 = ws + 1048576 + 32768 + 1048576;   // 1,048,576 floats
    float4* probs4 = (float4*)(out + CTX_FLOATS);

    void* args[] = {
        (void*)&q, (void*)&k, (void*)&v, (void*)&W, (void*)&bias,
        (void*)&out, (void*)&S16, (void*)&ksum_ws, (void*)&Ptg,
        (void*)&attn2, (void*)&probs4
    };
    hipLaunchCooperativeKernel((const void*)k_fused, dim3(512), dim3(256),
                               args, 0, stream);
}

// Round 6
// 113.510 us; speedup vs baseline: 2.7269x; 2.7269x over previous
//
#include <hip/hip_runtime.h>

#define TSEQ 1024
#define HIDV 64
#define NHEADS 16      // N*H = 2*8
#define LCH 64         // chunk length
#define NCH 16         // TSEQ/LCH
#define EMBED 512
#define CTX_FLOATS (NHEADS * TSEQ * HIDV)           // 1048576
#define EPSV 1e-6f
#define PIH 1.5707963267948966f

typedef short bf16x8 __attribute__((ext_vector_type(8)));
typedef float f32x4 __attribute__((ext_vector_type(4)));

__device__ __forceinline__ float relu_f(float x) { return fmaxf(x, 0.0f); }
__device__ __forceinline__ ushort f2bf(float f) {
    uint u = __float_as_uint(f);
    u += 0x7FFF + ((u >> 16) & 1);          // RNE
    return (ushort)(u >> 16);
}
__device__ __forceinline__ float bf2f(ushort h) { return __uint_as_float(((uint)h) << 16); }
__device__ __forceinline__ uint pk2(float a, float b) {
    return (uint)f2bf(a) | ((uint)f2bf(b) << 16);
}

// ---------------------------------------------------------------------------
// Kernel 1: chunk sums, m-half split. block (pair,mh): S^T[m 32][dd 128] bf16.
// grid 512 x 256.  Probs-zero slice 0 (16 MB).
// ---------------------------------------------------------------------------
__global__ __launch_bounds__(256) void k1_chunksum(
    const float* __restrict__ K, const float* __restrict__ V,
    ushort* __restrict__ S16, float* __restrict__ ksumws,
    float4* __restrict__ probs4)
{
    __shared__ ushort kwT[128 * 88];   // [dd][i] weighted bf16
    __shared__ ushort vT1[32 * 88];    // [m-half][i]
    const int bid = blockIdx.x;
    const int tid = threadIdx.x;

    {   // probs zero slice 0
        float4 z = make_float4(0.f, 0.f, 0.f, 0.f);
        size_t base = (size_t)bid * 2048 + tid;
        #pragma unroll
        for (int s = 0; s < 8; ++s) probs4[base + s * 256] = z;
    }

    const int pair = bid >> 1, mh = bid & 1, m0b = mh * 32;
    const int b = pair >> 4, c = pair & 15;
    const int l0 = c * LCH;

    #pragma unroll
    for (int s = 0; s < 4; ++s) {
        int e = tid + s * 256;               // f4 over 64x64
        int i = e >> 4, d = (e & 15) * 4;
        float4 k4 = *(const float4*)(K + (size_t)(b * TSEQ + l0 + i) * HIDV + d);
        float si, ci;
        __sincosf(PIH * (float)(l0 + i + 1) * (1.0f / 1024.0f), &si, &ci);
        float kv[4] = {relu_f(k4.x), relu_f(k4.y), relu_f(k4.z), relu_f(k4.w)};
        #pragma unroll
        for (int j = 0; j < 4; ++j) {
            kwT[(d + j) * 88 + i] = f2bf(si * kv[j]);
            kwT[(d + 64 + j) * 88 + i] = f2bf(ci * kv[j]);
        }
    }
    #pragma unroll
    for (int s = 0; s < 2; ++s) {
        int e = tid + s * 256;               // f4 over 64 i x 32 m
        int i = e >> 3, mf = (e & 7) * 4;
        float4 v4 = *(const float4*)(V + ((size_t)(l0 + i) * NHEADS + b) * HIDV + m0b + mf);
        vT1[(mf + 0) * 88 + i] = f2bf(v4.x);
        vT1[(mf + 1) * 88 + i] = f2bf(v4.y);
        vT1[(mf + 2) * 88 + i] = f2bf(v4.z);
        vT1[(mf + 3) * 88 + i] = f2bf(v4.w);
    }
    __syncthreads();

    const int w = tid >> 6, lane = tid & 63;
    const int quad = lane >> 4, l15 = lane & 15;

    bf16x8 bfv[2][2];
    #pragma unroll
    for (int mt = 0; mt < 2; ++mt)
        #pragma unroll
        for (int kk = 0; kk < 2; ++kk)
            bfv[mt][kk] = *(const bf16x8*)(vT1 + (mt * 16 + l15) * 88 + kk * 32 + quad * 8);

    f32x4 acc[2][2];
    #pragma unroll
    for (int ii = 0; ii < 2; ++ii)
        #pragma unroll
        for (int mt = 0; mt < 2; ++mt) acc[ii][mt] = (f32x4){0.f, 0.f, 0.f, 0.f};
    #pragma unroll
    for (int ii = 0; ii < 2; ++ii) {
        int itv = w + ii * 4;                // dd-tile 0..7
        #pragma unroll
        for (int kk = 0; kk < 2; ++kk) {
            bf16x8 af = *(const bf16x8*)(kwT + (itv * 16 + l15) * 88 + kk * 32 + quad * 8);
            #pragma unroll
            for (int mt = 0; mt < 2; ++mt)
                acc[ii][mt] = __builtin_amdgcn_mfma_f32_16x16x32_bf16(af, bfv[mt][kk], acc[ii][mt], 0, 0, 0);
        }
    }
    // store S^T bf16 [m][dd]
    ushort* SpT = S16 + (size_t)pair * 8192;
    #pragma unroll
    for (int ii = 0; ii < 2; ++ii)
        #pragma unroll
        for (int mt = 0; mt < 2; ++mt) {
            int m = m0b + mt * 16 + l15;
            int ddb = (w + ii * 4) * 16 + quad * 4;
            uint2 pk = make_uint2(pk2(acc[ii][mt][0], acc[ii][mt][1]),
                                  pk2(acc[ii][mt][2], acc[ii][mt][3]));
            *(uint2*)(SpT + m * 128 + ddb) = pk;
        }
    if (mh == 0 && tid < 128) {
        float ssum = 0.f;
        #pragma unroll
        for (int ss = 0; ss < 8; ++ss) {
            uint4 u = *(const uint4*)(kwT + tid * 88 + ss * 8);
            ssum += bf2f((ushort)(u.x & 0xffff)) + bf2f((ushort)(u.x >> 16));
            ssum += bf2f((ushort)(u.y & 0xffff)) + bf2f((ushort)(u.y >> 16));
            ssum += bf2f((ushort)(u.z & 0xffff)) + bf2f((ushort)(u.z >> 16));
            ssum += bf2f((ushort)(u.w & 0xffff)) + bf2f((ushort)(u.w >> 16));
        }
        ksumws[(size_t)pair * 128 + tid] = ssum;
    }
}

// ---------------------------------------------------------------------------
// Kernel 2: exclusive prefix scan (S16 -> Ptg bf16, ksum fp32) + W -> bf16.
// grid 512 x 256.  Probs-zero slice 1.
// ---------------------------------------------------------------------------
__global__ __launch_bounds__(256) void k2_scan(
    const ushort* __restrict__ S16, float* __restrict__ ksumws,
    ushort* __restrict__ Ptg, const float* __restrict__ W,
    ushort* __restrict__ W16, float4* __restrict__ probs4)
{
    {
        float4 z = make_float4(0.f, 0.f, 0.f, 0.f);
        size_t base = 1048576 + (size_t)blockIdx.x * 2048 + threadIdx.x;
        #pragma unroll
        for (int s = 0; s < 8; ++s) probs4[base + s * 256] = z;
    }
    int g = blockIdx.x * 256 + threadIdx.x;      // 0..131071
    {
        int bs = g >> 13, idx = g & 8191;
        const ushort* Sp = S16 + (size_t)bs * 131072 + idx;
        ushort* Pp = Ptg + (size_t)bs * 131072 + idx;
        float acc = 0.f;
        #pragma unroll
        for (int c = 0; c < NCH; ++c) {
            float t = bf2f(Sp[c * 8192]);
            Pp[c * 8192] = f2bf(acc);
            acc += t;
        }
    }
    if (g < 65536) {                             // W (512x512 fp32) -> bf16
        float4 w4 = *(const float4*)(W + (size_t)g * 4);
        *(uint2*)(W16 + (size_t)g * 4) = make_uint2(pk2(w4.x, w4.y), pk2(w4.z, w4.w));
    }
    if (g < NHEADS * 128) {
        int b2 = g >> 7, i2 = g & 127;
        float a2 = 0.f;
        #pragma unroll
        for (int c = 0; c < NCH; ++c) {
            float* p = ksumws + (size_t)(b2 * NCH + c) * 128 + i2;
            float t = *p; *p = a2; a2 += t;
        }
    }
}

// ---------------------------------------------------------------------------
// Kernel 3: attention, 2 blocks per (b,c) (m-halves).  grid 512 x 256.
// LDS 58368 B -> 2 blocks/CU.  Probs-zero slice 2.  attn2 stored bf16.
// ---------------------------------------------------------------------------
#define SMEM_BYTES 58368
#define OFF_QW 0          // ushort[64*136]
#define OFF_KW 17408      // ushort[64*136]
#define OFF_PT 34816      // ushort[32*136]
#define OFF_VT 43520      // ushort[32*72]
#define OFF_AM 48128      // ushort[64*72]
#define OFF_PSUM 57344    // float[128]
#define OFF_DENA 57856    // float[64]
#define OFF_DENI 58112    // float[64]

__global__ __launch_bounds__(256) void k3_attn(
    const float* __restrict__ Q, const float* __restrict__ K,
    const float* __restrict__ V,
    const ushort* __restrict__ Ptg, const float* __restrict__ ksumws,
    ushort* __restrict__ attn216, float4* __restrict__ probs4)
{
    __shared__ __align__(16) char smem[SMEM_BYTES];
    ushort* qw = (ushort*)(smem + OFF_QW);
    ushort* kw = (ushort*)(smem + OFF_KW);
    ushort* Pt = (ushort*)(smem + OFF_PT);
    ushort* vT = (ushort*)(smem + OFF_VT);
    ushort* Am = (ushort*)(smem + OFF_AM);
    float* psum = (float*)(smem + OFF_PSUM);
    float* denA = (float*)(smem + OFF_DENA);
    float* denI = (float*)(smem + OFF_DENI);

    const int bid = blockIdx.x;
    const int tid = threadIdx.x;
    const int w = tid >> 6, lane = tid & 63;
    const int quad = lane >> 4, l15 = lane & 15;

    {
        float4 z = make_float4(0.f, 0.f, 0.f, 0.f);
        size_t base = 2097152 + (size_t)bid * 2048 + tid;
        #pragma unroll
        for (int s = 0; s < 8; ++s) probs4[base + s * 256] = z;
    }

    const int pair = bid >> 1, mh = bid & 1, m0b = mh * 32;
    const int b = pair >> 4, c = pair & 15;
    const int l0 = c * LCH;

    #pragma unroll
    for (int s = 0; s < 4; ++s) {
        int e = tid + s * 256;
        int i = e >> 4, d = (e & 15) * 4;
        float si, ci;
        __sincosf(PIH * (float)(l0 + i + 1) * (1.0f / 1024.0f), &si, &ci);
        float4 q4 = *(const float4*)(Q + (size_t)(b * TSEQ + l0 + i) * HIDV + d);
        float qv[4] = {relu_f(q4.x), relu_f(q4.y), relu_f(q4.z), relu_f(q4.w)};
        *(uint2*)(qw + i * 136 + d) = make_uint2(pk2(si * qv[0], si * qv[1]), pk2(si * qv[2], si * qv[3]));
        *(uint2*)(qw + i * 136 + 64 + d) = make_uint2(pk2(ci * qv[0], ci * qv[1]), pk2(ci * qv[2], ci * qv[3]));
        float4 k4 = *(const float4*)(K + (size_t)(b * TSEQ + l0 + i) * HIDV + d);
        float kv[4] = {relu_f(k4.x), relu_f(k4.y), relu_f(k4.z), relu_f(k4.w)};
        *(uint2*)(kw + i * 136 + d) = make_uint2(pk2(si * kv[0], si * kv[1]), pk2(si * kv[2], si * kv[3]));
        *(uint2*)(kw + i * 136 + 64 + d) = make_uint2(pk2(ci * kv[0], ci * kv[1]), pk2(ci * kv[2], ci * kv[3]));
    }
    {   // Pt: uint4 copies, 32 rows x 128 dd
        const ushort* Pg = Ptg + (size_t)pair * 8192;
        #pragma unroll
        for (int s = 0; s < 2; ++s) {
            int e = tid + s * 256;
            int mrow = e >> 4, dd8 = (e & 15) * 8;
            *(uint4*)(Pt + mrow * 136 + dd8) = *(const uint4*)(Pg + (m0b + mrow) * 128 + dd8);
        }
    }
    #pragma unroll
    for (int s = 0; s < 2; ++s) {
        int e = tid + s * 256;
        int j = e >> 3, mf = (e & 7) * 4;
        float4 v4 = *(const float4*)(V + ((size_t)(l0 + j) * NHEADS + b) * HIDV + m0b + mf);
        vT[(mf + 0) * 72 + j] = f2bf(v4.x);
        vT[(mf + 1) * 72 + j] = f2bf(v4.y);
        vT[(mf + 2) * 72 + j] = f2bf(v4.z);
        vT[(mf + 3) * 72 + j] = f2bf(v4.w);
    }
    if (tid < 128) psum[tid] = ksumws[(size_t)pair * 128 + tid];
    __syncthreads();

    const int it = w;
    bf16x8 af[4];
    #pragma unroll
    for (int kk = 0; kk < 4; ++kk)
        af[kk] = *(const bf16x8*)(qw + (it * 16 + l15) * 136 + kk * 32 + quad * 8);

    // QK^T
    f32x4 accA[4];
    #pragma unroll
    for (int jt = 0; jt < 4; ++jt) {
        accA[jt] = (f32x4){0.f, 0.f, 0.f, 0.f};
        #pragma unroll
        for (int kk = 0; kk < 4; ++kk) {
            bf16x8 bf = *(const bf16x8*)(kw + (jt * 16 + l15) * 136 + kk * 32 + quad * 8);
            accA[jt] = __builtin_amdgcn_mfma_f32_16x16x32_bf16(af[kk], bf, accA[jt], 0, 0, 0);
        }
    }
    // mask + Am + row sums
    {
        float rsum[4] = {0.f, 0.f, 0.f, 0.f};
        #pragma unroll
        for (int jt = 0; jt < 4; ++jt) {
            int j = jt * 16 + l15;
            #pragma unroll
            for (int r = 0; r < 4; ++r) {
                int i = it * 16 + quad * 4 + r;
                float val = (j <= i) ? accA[jt][r] : 0.f;
                Am[i * 72 + j] = f2bf(val);
                rsum[r] += val;
            }
        }
        #pragma unroll
        for (int off = 1; off < 16; off <<= 1) {
            rsum[0] += __shfl_xor(rsum[0], off);
            rsum[1] += __shfl_xor(rsum[1], off);
            rsum[2] += __shfl_xor(rsum[2], off);
            rsum[3] += __shfl_xor(rsum[3], off);
        }
        if (l15 == 0) {
            #pragma unroll
            for (int r = 0; r < 4; ++r) denA[it * 16 + quad * 4 + r] = rsum[r];
        }
    }
    if (tid < 64) {
        float s = 0.f;
        #pragma unroll
        for (int ss = 0; ss < 16; ++ss) {
            uint4 u = *(const uint4*)(qw + tid * 136 + ss * 8);
            s += bf2f((ushort)(u.x & 0xffff)) * psum[ss * 8 + 0] + bf2f((ushort)(u.x >> 16)) * psum[ss * 8 + 1];
            s += bf2f((ushort)(u.y & 0xffff)) * psum[ss * 8 + 2] + bf2f((ushort)(u.y >> 16)) * psum[ss * 8 + 3];
            s += bf2f((ushort)(u.z & 0xffff)) * psum[ss * 8 + 4] + bf2f((ushort)(u.z >> 16)) * psum[ss * 8 + 5];
            s += bf2f((ushort)(u.w & 0xffff)) * psum[ss * 8 + 6] + bf2f((ushort)(u.w >> 16)) * psum[ss * 8 + 7];
        }
        denI[tid] = s;
    }
    __syncthreads();

    // O = qw*P + Am*V
    f32x4 accO[2];
    #pragma unroll
    for (int mm = 0; mm < 2; ++mm) {
        accO[mm] = (f32x4){0.f, 0.f, 0.f, 0.f};
        #pragma unroll
        for (int kk = 0; kk < 4; ++kk) {
            bf16x8 bp = *(const bf16x8*)(Pt + (mm * 16 + l15) * 136 + kk * 32 + quad * 8);
            accO[mm] = __builtin_amdgcn_mfma_f32_16x16x32_bf16(af[kk], bp, accO[mm], 0, 0, 0);
        }
    }
    bf16x8 aA[2];
    #pragma unroll
    for (int kk = 0; kk < 2; ++kk)
        aA[kk] = *(const bf16x8*)(Am + (it * 16 + l15) * 72 + kk * 32 + quad * 8);
    #pragma unroll
    for (int mm = 0; mm < 2; ++mm)
        #pragma unroll
        for (int kk = 0; kk < 2; ++kk) {
            bf16x8 bv = *(const bf16x8*)(vT + (mm * 16 + l15) * 72 + kk * 32 + quad * 8);
            accO[mm] = __builtin_amdgcn_mfma_f32_16x16x32_bf16(aA[kk], bv, accO[mm], 0, 0, 0);
        }

    const int nb = b >> 3, hh = b & 7;
    #pragma unroll
    for (int r = 0; r < 4; ++r) {
        int i = it * 16 + quad * 4 + r;
        float inv = 1.0f / fmaxf(denA[i] + denI[i], EPSV);
        #pragma unroll
        for (int mm = 0; mm < 2; ++mm) {
            int m = m0b + mm * 16 + l15;
            attn216[(size_t)((l0 + i) * 2 + nb) * EMBED + hh * 64 + m] = f2bf(accO[mm][r] * inv);
        }
    }
}

// ---------------------------------------------------------------------------
// Kernel 4: out projection from bf16 attn2 and bf16 W.  32x64 tiles,
// grid 512 x 256.  Probs-zero slice 3.
// ---------------------------------------------------------------------------
__global__ __launch_bounds__(256) void k4_outproj(
    const ushort* __restrict__ A16, const ushort* __restrict__ W16,
    const float* __restrict__ bias, float* __restrict__ out,
    float4* __restrict__ probs4)
{
    __shared__ ushort Ab[32 * 72];
    __shared__ ushort Bb[64 * 72];
    const int bid = blockIdx.x;
    const int tid = threadIdx.x;
    {
        float4 z = make_float4(0.f, 0.f, 0.f, 0.f);
        size_t base = 3145728 + (size_t)bid * 2048 + tid;
        #pragma unroll
        for (int s = 0; s < 8; ++s) probs4[base + s * 256] = z;
    }
    const int rt = bid >> 3, et = bid & 7;
    const int r0 = rt * 32, e0 = et * 64;
    const int w = tid >> 6, lane = tid & 63;
    const int quad = lane >> 4, l15 = lane & 15;
    const int it4 = w >> 1, jt0 = (w & 1) * 2;
    f32x4 acc4[2];
    acc4[0] = (f32x4){0.f, 0.f, 0.f, 0.f};
    acc4[1] = (f32x4){0.f, 0.f, 0.f, 0.f};

    for (int f0 = 0; f0 < EMBED; f0 += 64) {
        __syncthreads();
        {   // Ab: 32x64 bf16 = 256 uint4
            int rr = tid >> 3, ff = (tid & 7) * 8;
            *(uint4*)(Ab + rr * 72 + ff) = *(const uint4*)(A16 + (size_t)(r0 + rr) * EMBED + f0 + ff);
        }
        #pragma unroll
        for (int s = 0; s < 2; ++s) {   // Bb: 64x64 bf16 = 512 uint4
            int e = tid + s * 256;
            int rr = e >> 3, ff = (e & 7) * 8;
            *(uint4*)(Bb + rr * 72 + ff) = *(const uint4*)(W16 + (size_t)(e0 + rr) * EMBED + f0 + ff);
        }
        __syncthreads();
        bf16x8 af2[2];
        #pragma unroll
        for (int kk = 0; kk < 2; ++kk)
            af2[kk] = *(const bf16x8*)(Ab + (it4 * 16 + l15) * 72 + kk * 32 + quad * 8);
        #pragma unroll
        for (int jj = 0; jj < 2; ++jj) {
            int jt = jt0 + jj;
            #pragma unroll
            for (int kk = 0; kk < 2; ++kk) {
                bf16x8 bf = *(const bf16x8*)(Bb + (jt * 16 + l15) * 72 + kk * 32 + quad * 8);
                acc4[jj] = __builtin_amdgcn_mfma_f32_16x16x32_bf16(af2[kk], bf, acc4[jj], 0, 0, 0);
            }
        }
    }
    #pragma unroll
    for (int jj = 0; jj < 2; ++jj) {
        int e = e0 + (jt0 + jj) * 16 + l15;
        float be = bias[e];
        int h = e >> 6, m = e & 63;
        #pragma unroll
        for (int r = 0; r < 4; ++r) {
            int rr = r0 + it4 * 16 + quad * 4 + r;
            int t = rr >> 1, n = rr & 1;
            out[((size_t)(n * 8 + h) * TSEQ + t) * HIDV + m] = acc4[jj][r] + be;
        }
    }
}

// ---------------------------------------------------------------------------
extern "C" void kernel_launch(void* const* d_in, const int* in_sizes, int n_in,
                              void* d_out, int out_size, void* d_ws, size_t ws_size,
                              hipStream_t stream) {
    const float* q = (const float*)d_in[0];
    const float* k = (const float*)d_in[1];
    const float* v = (const float*)d_in[2];
    const float* W = (const float*)d_in[3];
    const float* bias = (const float*)d_in[4];
    float* out = (float*)d_out;
    float* ws = (float*)d_ws;

    ushort* S16 = (ushort*)ws;                        // 2,097,152 bf16 (4 MB)
    float* ksum_ws = ws + 1048576;                    // 32,768 fp32
    ushort* Ptg = (ushort*)(ws + 1081344);            // 2,097,152 bf16 (4 MB)
    ushort* attn216 = (ushort*)(ws + 2129920);        // 1,048,576 bf16 (2 MB)
    ushort* W16 = (ushort*)(ws + 2654208);            // 262,144 bf16 (0.5 MB)
    float4* probs4 = (float4*)(out + CTX_FLOATS);

    k1_chunksum<<<dim3(512), dim3(256), 0, stream>>>(k, v, S16, ksum_ws, probs4);
    k2_scan<<<dim3(512), dim3(256), 0, stream>>>(S16, ksum_ws, Ptg, W, W16, probs4);
    k3_attn<<<dim3(512), dim3(256), 0, stream>>>(q, k, v, Ptg, ksum_ws, attn216, probs4);
    k4_outproj<<<dim3(512), dim3(256), 0, stream>>>(attn216, W16, bias, out, probs4);
}

// Round 7
// 113.061 us; speedup vs baseline: 2.7377x; 1.0040x over previous
//
#include <hip/hip_runtime.h>

#define TSEQ 1024
#define HIDV 64
#define NHEADS 16      // N*H = 2*8
#define LCH 64         // chunk length
#define NCH 16         // TSEQ/LCH
#define EMBED 512
#define CTX_FLOATS (NHEADS * TSEQ * HIDV)           // 1048576
#define EPSV 1e-6f
#define PIH 1.5707963267948966f

typedef short bf16x8 __attribute__((ext_vector_type(8)));
typedef float f32x4 __attribute__((ext_vector_type(4)));

__device__ __forceinline__ float relu_f(float x) { return fmaxf(x, 0.0f); }
__device__ __forceinline__ ushort f2bf(float f) {
    uint u = __float_as_uint(f);
    u += 0x7FFF + ((u >> 16) & 1);          // RNE
    return (ushort)(u >> 16);
}
__device__ __forceinline__ float bf2f(ushort h) { return __uint_as_float(((uint)h) << 16); }
__device__ __forceinline__ uint pk2(float a, float b) {
    return (uint)f2bf(a) | ((uint)f2bf(b) << 16);
}

// ---------------------------------------------------------------------------
// Kernel A: chunk sums (m-half split) + W->bf16 + probs-zero slice 0.
// grid 512 x 256.  S^T stored bf16 [m][dd] per (b,c); ksum raw per-chunk.
// ---------------------------------------------------------------------------
__global__ __launch_bounds__(256) void kA_chunksum(
    const float* __restrict__ K, const float* __restrict__ V,
    const float* __restrict__ W,
    ushort* __restrict__ S16, float* __restrict__ ksumws,
    ushort* __restrict__ W16, float4* __restrict__ probs4)
{
    __shared__ ushort kwT[128 * 88];   // [dd][i] weighted bf16
    __shared__ ushort vT1[32 * 88];    // [m-half][i]
    const int bid = blockIdx.x;
    const int tid = threadIdx.x;

    {   // probs zero slice 0: 1,310,720 f4 (20 MB)
        float4 z = make_float4(0.f, 0.f, 0.f, 0.f);
        size_t base = (size_t)bid * 2560 + tid;
        #pragma unroll
        for (int s = 0; s < 10; ++s) probs4[base + s * 256] = z;
    }
    {   // W (512x512 fp32) -> bf16: 65536 f4 over 512 blocks
        int g = bid * 128 + (tid & 127);
        if (tid < 128) {
            float4 w4 = *(const float4*)(W + (size_t)g * 4);
            *(uint2*)(W16 + (size_t)g * 4) = make_uint2(pk2(w4.x, w4.y), pk2(w4.z, w4.w));
        }
    }

    const int pair = bid >> 1, mh = bid & 1, m0b = mh * 32;
    const int b = pair >> 4, c = pair & 15;
    const int l0 = c * LCH;

    #pragma unroll
    for (int s = 0; s < 4; ++s) {
        int e = tid + s * 256;               // f4 over 64x64
        int i = e >> 4, d = (e & 15) * 4;
        float4 k4 = *(const float4*)(K + (size_t)(b * TSEQ + l0 + i) * HIDV + d);
        float si, ci;
        __sincosf(PIH * (float)(l0 + i + 1) * (1.0f / 1024.0f), &si, &ci);
        float kv[4] = {relu_f(k4.x), relu_f(k4.y), relu_f(k4.z), relu_f(k4.w)};
        #pragma unroll
        for (int j = 0; j < 4; ++j) {
            kwT[(d + j) * 88 + i] = f2bf(si * kv[j]);
            kwT[(d + 64 + j) * 88 + i] = f2bf(ci * kv[j]);
        }
    }
    #pragma unroll
    for (int s = 0; s < 2; ++s) {
        int e = tid + s * 256;               // f4 over 64 i x 32 m
        int i = e >> 3, mf = (e & 7) * 4;
        float4 v4 = *(const float4*)(V + ((size_t)(l0 + i) * NHEADS + b) * HIDV + m0b + mf);
        vT1[(mf + 0) * 88 + i] = f2bf(v4.x);
        vT1[(mf + 1) * 88 + i] = f2bf(v4.y);
        vT1[(mf + 2) * 88 + i] = f2bf(v4.z);
        vT1[(mf + 3) * 88 + i] = f2bf(v4.w);
    }
    __syncthreads();

    const int w = tid >> 6, lane = tid & 63;
    const int quad = lane >> 4, l15 = lane & 15;

    bf16x8 bfv[2][2];
    #pragma unroll
    for (int mt = 0; mt < 2; ++mt)
        #pragma unroll
        for (int kk = 0; kk < 2; ++kk)
            bfv[mt][kk] = *(const bf16x8*)(vT1 + (mt * 16 + l15) * 88 + kk * 32 + quad * 8);

    f32x4 acc[2][2];
    #pragma unroll
    for (int ii = 0; ii < 2; ++ii)
        #pragma unroll
        for (int mt = 0; mt < 2; ++mt) acc[ii][mt] = (f32x4){0.f, 0.f, 0.f, 0.f};
    #pragma unroll
    for (int ii = 0; ii < 2; ++ii) {
        int itv = w + ii * 4;                // dd-tile 0..7
        #pragma unroll
        for (int kk = 0; kk < 2; ++kk) {
            bf16x8 af = *(const bf16x8*)(kwT + (itv * 16 + l15) * 88 + kk * 32 + quad * 8);
            #pragma unroll
            for (int mt = 0; mt < 2; ++mt)
                acc[ii][mt] = __builtin_amdgcn_mfma_f32_16x16x32_bf16(af, bfv[mt][kk], acc[ii][mt], 0, 0, 0);
        }
    }
    ushort* SpT = S16 + (size_t)pair * 8192;
    #pragma unroll
    for (int ii = 0; ii < 2; ++ii)
        #pragma unroll
        for (int mt = 0; mt < 2; ++mt) {
            int m = m0b + mt * 16 + l15;
            int ddb = (w + ii * 4) * 16 + quad * 4;
            uint2 pk = make_uint2(pk2(acc[ii][mt][0], acc[ii][mt][1]),
                                  pk2(acc[ii][mt][2], acc[ii][mt][3]));
            *(uint2*)(SpT + m * 128 + ddb) = pk;
        }
    if (mh == 0 && tid < 128) {
        float ssum = 0.f;
        #pragma unroll
        for (int ss = 0; ss < 8; ++ss) {
            uint4 u = *(const uint4*)(kwT + tid * 88 + ss * 8);
            ssum += bf2f((ushort)(u.x & 0xffff)) + bf2f((ushort)(u.x >> 16));
            ssum += bf2f((ushort)(u.y & 0xffff)) + bf2f((ushort)(u.y >> 16));
            ssum += bf2f((ushort)(u.z & 0xffff)) + bf2f((ushort)(u.z >> 16));
            ssum += bf2f((ushort)(u.w & 0xffff)) + bf2f((ushort)(u.w >> 16));
        }
        ksumws[(size_t)pair * 128 + tid] = ssum;
    }
}

// ---------------------------------------------------------------------------
// Kernel B: attention with INLINE prefix (no scan kernel).  2 blocks per
// (b,c): m-halves.  grid 512 x 256.  LDS 58368 B -> 2 blocks/CU.
// Probs-zero slice 1.  attn2 stored bf16.
// ---------------------------------------------------------------------------
#define SMEM_BYTES 58368
#define OFF_QW 0          // ushort[64*136]
#define OFF_KW 17408      // ushort[64*136]
#define OFF_PT 34816      // ushort[32*136]
#define OFF_VT 43520      // ushort[32*72]
#define OFF_AM 48128      // ushort[64*72]
#define OFF_PSUM 57344    // float[128]
#define OFF_DENA 57856    // float[64]
#define OFF_DENI 58112    // float[64]

__global__ __launch_bounds__(256) void kB_attn(
    const float* __restrict__ Q, const float* __restrict__ K,
    const float* __restrict__ V,
    const ushort* __restrict__ S16, const float* __restrict__ ksumws,
    ushort* __restrict__ attn216, float4* __restrict__ probs4)
{
    __shared__ __align__(16) char smem[SMEM_BYTES];
    ushort* qw = (ushort*)(smem + OFF_QW);
    ushort* kw = (ushort*)(smem + OFF_KW);
    ushort* Pt = (ushort*)(smem + OFF_PT);
    ushort* vT = (ushort*)(smem + OFF_VT);
    ushort* Am = (ushort*)(smem + OFF_AM);
    float* psum = (float*)(smem + OFF_PSUM);
    float* denA = (float*)(smem + OFF_DENA);
    float* denI = (float*)(smem + OFF_DENI);

    const int bid = blockIdx.x;
    const int tid = threadIdx.x;
    const int w = tid >> 6, lane = tid & 63;
    const int quad = lane >> 4, l15 = lane & 15;

    {   // probs zero slice 1: 1,310,720 f4
        float4 z = make_float4(0.f, 0.f, 0.f, 0.f);
        size_t base = 1310720 + (size_t)bid * 2560 + tid;
        #pragma unroll
        for (int s = 0; s < 10; ++s) probs4[base + s * 256] = z;
    }

    const int pair = bid >> 1, mh = bid & 1, m0b = mh * 32;
    const int b = pair >> 4, c = pair & 15;
    const int l0 = c * LCH;

    // --- inline exclusive prefix: P[ml][dd] = sum_{cp<c} S[b][cp][m0b+ml][dd]
    {
        const int ml = tid >> 3, dd0 = (tid & 7) * 16;
        const ushort* Sb = S16 + ((size_t)b * NCH) * 8192 + (m0b + ml) * 128 + dd0;
        float accp[16];
        #pragma unroll
        for (int u = 0; u < 16; ++u) accp[u] = 0.f;
        for (int cp = 0; cp < c; ++cp) {
            const ushort* Sp = Sb + (size_t)cp * 8192;
            uint4 u0 = *(const uint4*)(Sp);
            uint4 u1 = *(const uint4*)(Sp + 8);
            uint uu[8] = {u0.x, u0.y, u0.z, u0.w, u1.x, u1.y, u1.z, u1.w};
            #pragma unroll
            for (int p = 0; p < 8; ++p) {
                accp[p * 2 + 0] += bf2f((ushort)(uu[p] & 0xffff));
                accp[p * 2 + 1] += bf2f((ushort)(uu[p] >> 16));
            }
        }
        uint pkv[8];
        #pragma unroll
        for (int p = 0; p < 8; ++p) pkv[p] = pk2(accp[p * 2], accp[p * 2 + 1]);
        *(uint4*)(Pt + ml * 136 + dd0) = make_uint4(pkv[0], pkv[1], pkv[2], pkv[3]);
        *(uint4*)(Pt + ml * 136 + dd0 + 8) = make_uint4(pkv[4], pkv[5], pkv[6], pkv[7]);
    }
    if (tid < 128) {
        float s = 0.f;
        const float* Kb = ksumws + (size_t)b * NCH * 128 + tid;
        for (int cp = 0; cp < c; ++cp) s += Kb[cp * 128];
        psum[tid] = s;
    }

    #pragma unroll
    for (int s = 0; s < 4; ++s) {
        int e = tid + s * 256;
        int i = e >> 4, d = (e & 15) * 4;
        float si, ci;
        __sincosf(PIH * (float)(l0 + i + 1) * (1.0f / 1024.0f), &si, &ci);
        float4 q4 = *(const float4*)(Q + (size_t)(b * TSEQ + l0 + i) * HIDV + d);
        float qv[4] = {relu_f(q4.x), relu_f(q4.y), relu_f(q4.z), relu_f(q4.w)};
        *(uint2*)(qw + i * 136 + d) = make_uint2(pk2(si * qv[0], si * qv[1]), pk2(si * qv[2], si * qv[3]));
        *(uint2*)(qw + i * 136 + 64 + d) = make_uint2(pk2(ci * qv[0], ci * qv[1]), pk2(ci * qv[2], ci * qv[3]));
        float4 k4 = *(const float4*)(K + (size_t)(b * TSEQ + l0 + i) * HIDV + d);
        float kv[4] = {relu_f(k4.x), relu_f(k4.y), relu_f(k4.z), relu_f(k4.w)};
        *(uint2*)(kw + i * 136 + d) = make_uint2(pk2(si * kv[0], si * kv[1]), pk2(si * kv[2], si * kv[3]));
        *(uint2*)(kw + i * 136 + 64 + d) = make_uint2(pk2(ci * kv[0], ci * kv[1]), pk2(ci * kv[2], ci * kv[3]));
    }
    #pragma unroll
    for (int s = 0; s < 2; ++s) {
        int e = tid + s * 256;
        int j = e >> 3, mf = (e & 7) * 4;
        float4 v4 = *(const float4*)(V + ((size_t)(l0 + j) * NHEADS + b) * HIDV + m0b + mf);
        vT[(mf + 0) * 72 + j] = f2bf(v4.x);
        vT[(mf + 1) * 72 + j] = f2bf(v4.y);
        vT[(mf + 2) * 72 + j] = f2bf(v4.z);
        vT[(mf + 3) * 72 + j] = f2bf(v4.w);
    }
    __syncthreads();

    const int it = w;
    bf16x8 af[4];
    #pragma unroll
    for (int kk = 0; kk < 4; ++kk)
        af[kk] = *(const bf16x8*)(qw + (it * 16 + l15) * 136 + kk * 32 + quad * 8);

    // QK^T
    f32x4 accA[4];
    #pragma unroll
    for (int jt = 0; jt < 4; ++jt) {
        accA[jt] = (f32x4){0.f, 0.f, 0.f, 0.f};
        #pragma unroll
        for (int kk = 0; kk < 4; ++kk) {
            bf16x8 bf = *(const bf16x8*)(kw + (jt * 16 + l15) * 136 + kk * 32 + quad * 8);
            accA[jt] = __builtin_amdgcn_mfma_f32_16x16x32_bf16(af[kk], bf, accA[jt], 0, 0, 0);
        }
    }
    // mask + Am + row sums
    {
        float rsum[4] = {0.f, 0.f, 0.f, 0.f};
        #pragma unroll
        for (int jt = 0; jt < 4; ++jt) {
            int j = jt * 16 + l15;
            #pragma unroll
            for (int r = 0; r < 4; ++r) {
                int i = it * 16 + quad * 4 + r;
                float val = (j <= i) ? accA[jt][r] : 0.f;
                Am[i * 72 + j] = f2bf(val);
                rsum[r] += val;
            }
        }
        #pragma unroll
        for (int off = 1; off < 16; off <<= 1) {
            rsum[0] += __shfl_xor(rsum[0], off);
            rsum[1] += __shfl_xor(rsum[1], off);
            rsum[2] += __shfl_xor(rsum[2], off);
            rsum[3] += __shfl_xor(rsum[3], off);
        }
        if (l15 == 0) {
            #pragma unroll
            for (int r = 0; r < 4; ++r) denA[it * 16 + quad * 4 + r] = rsum[r];
        }
    }
    if (tid < 64) {
        float s = 0.f;
        #pragma unroll
        for (int ss = 0; ss < 16; ++ss) {
            uint4 u = *(const uint4*)(qw + tid * 136 + ss * 8);
            s += bf2f((ushort)(u.x & 0xffff)) * psum[ss * 8 + 0] + bf2f((ushort)(u.x >> 16)) * psum[ss * 8 + 1];
            s += bf2f((ushort)(u.y & 0xffff)) * psum[ss * 8 + 2] + bf2f((ushort)(u.y >> 16)) * psum[ss * 8 + 3];
            s += bf2f((ushort)(u.z & 0xffff)) * psum[ss * 8 + 4] + bf2f((ushort)(u.z >> 16)) * psum[ss * 8 + 5];
            s += bf2f((ushort)(u.w & 0xffff)) * psum[ss * 8 + 6] + bf2f((ushort)(u.w >> 16)) * psum[ss * 8 + 7];
        }
        denI[tid] = s;
    }
    __syncthreads();

    // O = qw*P + Am*V
    f32x4 accO[2];
    #pragma unroll
    for (int mm = 0; mm < 2; ++mm) {
        accO[mm] = (f32x4){0.f, 0.f, 0.f, 0.f};
        #pragma unroll
        for (int kk = 0; kk < 4; ++kk) {
            bf16x8 bp = *(const bf16x8*)(Pt + (mm * 16 + l15) * 136 + kk * 32 + quad * 8);
            accO[mm] = __builtin_amdgcn_mfma_f32_16x16x32_bf16(af[kk], bp, accO[mm], 0, 0, 0);
        }
    }
    bf16x8 aA[2];
    #pragma unroll
    for (int kk = 0; kk < 2; ++kk)
        aA[kk] = *(const bf16x8*)(Am + (it * 16 + l15) * 72 + kk * 32 + quad * 8);
    #pragma unroll
    for (int mm = 0; mm < 2; ++mm)
        #pragma unroll
        for (int kk = 0; kk < 2; ++kk) {
            bf16x8 bv = *(const bf16x8*)(vT + (mm * 16 + l15) * 72 + kk * 32 + quad * 8);
            accO[mm] = __builtin_amdgcn_mfma_f32_16x16x32_bf16(aA[kk], bv, accO[mm], 0, 0, 0);
        }

    const int nb = b >> 3, hh = b & 7;
    #pragma unroll
    for (int r = 0; r < 4; ++r) {
        int i = it * 16 + quad * 4 + r;
        float inv = 1.0f / fmaxf(denA[i] + denI[i], EPSV);
        #pragma unroll
        for (int mm = 0; mm < 2; ++mm) {
            int m = m0b + mm * 16 + l15;
            attn216[(size_t)((l0 + i) * 2 + nb) * EMBED + hh * 64 + m] = f2bf(accO[mm][r] * inv);
        }
    }
}

// ---------------------------------------------------------------------------
// Kernel C: out projection (bf16 x bf16).  32x64 tiles, grid 512 x 256.
// Probs-zero slice 2.
// ---------------------------------------------------------------------------
__global__ __launch_bounds__(256) void kC_outproj(
    const ushort* __restrict__ A16, const ushort* __restrict__ W16,
    const float* __restrict__ bias, float* __restrict__ out,
    float4* __restrict__ probs4)
{
    __shared__ ushort Ab[32 * 72];
    __shared__ ushort Bb[64 * 72];
    const int bid = blockIdx.x;
    const int tid = threadIdx.x;
    {   // probs zero slice 2: 1,572,864 f4
        float4 z = make_float4(0.f, 0.f, 0.f, 0.f);
        size_t base = 2621440 + (size_t)bid * 3072 + tid;
        #pragma unroll
        for (int s = 0; s < 12; ++s) probs4[base + s * 256] = z;
    }
    const int rt = bid >> 3, et = bid & 7;
    const int r0 = rt * 32, e0 = et * 64;
    const int w = tid >> 6, lane = tid & 63;
    const int quad = lane >> 4, l15 = lane & 15;
    const int it4 = w >> 1, jt0 = (w & 1) * 2;
    f32x4 acc4[2];
    acc4[0] = (f32x4){0.f, 0.f, 0.f, 0.f};
    acc4[1] = (f32x4){0.f, 0.f, 0.f, 0.f};

    for (int f0 = 0; f0 < EMBED; f0 += 64) {
        __syncthreads();
        {   // Ab: 32x64 bf16 = 256 uint4
            int rr = tid >> 3, ff = (tid & 7) * 8;
            *(uint4*)(Ab + rr * 72 + ff) = *(const uint4*)(A16 + (size_t)(r0 + rr) * EMBED + f0 + ff);
        }
        #pragma unroll
        for (int s = 0; s < 2; ++s) {   // Bb: 64x64 bf16 = 512 uint4
            int e = tid + s * 256;
            int rr = e >> 3, ff = (e & 7) * 8;
            *(uint4*)(Bb + rr * 72 + ff) = *(const uint4*)(W16 + (size_t)(e0 + rr) * EMBED + f0 + ff);
        }
        __syncthreads();
        bf16x8 af2[2];
        #pragma unroll
        for (int kk = 0; kk < 2; ++kk)
            af2[kk] = *(const bf16x8*)(Ab + (it4 * 16 + l15) * 72 + kk * 32 + quad * 8);
        #pragma unroll
        for (int jj = 0; jj < 2; ++jj) {
            int jt = jt0 + jj;
            #pragma unroll
            for (int kk = 0; kk < 2; ++kk) {
                bf16x8 bf = *(const bf16x8*)(Bb + (jt * 16 + l15) * 72 + kk * 32 + quad * 8);
                acc4[jj] = __builtin_amdgcn_mfma_f32_16x16x32_bf16(af2[kk], bf, acc4[jj], 0, 0, 0);
            }
        }
    }
    #pragma unroll
    for (int jj = 0; jj < 2; ++jj) {
        int e = e0 + (jt0 + jj) * 16 + l15;
        float be = bias[e];
        int h = e >> 6, m = e & 63;
        #pragma unroll
        for (int r = 0; r < 4; ++r) {
            int rr = r0 + it4 * 16 + quad * 4 + r;
            int t = rr >> 1, n = rr & 1;
            out[((size_t)(n * 8 + h) * TSEQ + t) * HIDV + m] = acc4[jj][r] + be;
        }
    }
}

// ---------------------------------------------------------------------------
extern "C" void kernel_launch(void* const* d_in, const int* in_sizes, int n_in,
                              void* d_out, int out_size, void* d_ws, size_t ws_size,
                              hipStream_t stream) {
    const float* q = (const float*)d_in[0];
    const float* k = (const float*)d_in[1];
    const float* v = (const float*)d_in[2];
    const float* W = (const float*)d_in[3];
    const float* bias = (const float*)d_in[4];
    float* out = (float*)d_out;
    float* ws = (float*)d_ws;

    ushort* S16 = (ushort*)ws;                        // 2,097,152 bf16 (4 MB)
    float* ksum_ws = ws + 1048576;                    // 32,768 fp32
    ushort* attn216 = (ushort*)(ws + 1081344);        // 1,048,576 bf16 (2 MB)
    ushort* W16 = (ushort*)(ws + 1605632);            // 262,144 bf16 (0.5 MB)
    float4* probs4 = (float4*)(out + CTX_FLOATS);

    kA_chunksum<<<dim3(512), dim3(256), 0, stream>>>(k, v, W, S16, ksum_ws, W16, probs4);
    kB_attn<<<dim3(512), dim3(256), 0, stream>>>(q, k, v, S16, ksum_ws, attn216, probs4);
    kC_outproj<<<dim3(512), dim3(256), 0, stream>>>(attn216, W16, bias, out, probs4);
}